// Round 1
// baseline (525.648 us; speedup 1.0000x reference)
//
#include <hip/hip_runtime.h>
#include <cstdint>
#include <math.h>

#define NIMG 32
#define CCH  256
#define HH_  56
#define HW   3136
#define NPIX 100352      // NIMG*HW
#define NELEM 25690112   // NIMG*CCH*HW

// ---- workspace layout (byte offsets) ----
#define OFF_PW1   0u           // 256*9*8 u32 = 73728
#define OFF_PW2   73728u       // 256*8 u32   = 8192
#define OFF_SC1   81920u       // 256 f32
#define OFF_SC2   82944u
#define OFF_A1    83968u
#define OFF_B1    84992u
#define OFF_A2    86016u
#define OFF_B2    87040u
#define OFF_ST    88064u       // st1: 64*256*2 ll = 262144 ; st2 follows
#define ST_BYTES  524288u
#define OFF_P1    612352u      // NPIX*8 u32 = 3211264
#define OFF_P2    3823616u
#define OFF_S1    7034880u     // NELEM i16 = 51380224
#define OFF_S2    58415104u
// total = 109795328 bytes (~104.7 MiB)

// ============ weight prep: scales + bit-packing (ballot) ============
__global__ void prep_w_k(const float* __restrict__ w3, const float* __restrict__ wr,
                         uint32_t* __restrict__ pw1, uint32_t* __restrict__ pw2,
                         float* __restrict__ sc1, float* __restrict__ sc2) {
  const int o = blockIdx.x, l = threadIdx.x;   // 64 threads = 1 wave
  const float* wo = w3 + (size_t)o * 2304;
  float s = 0.f;
  for (int i = l; i < 2304; i += 64) s += fabsf(wo[i]);
  for (int m = 32; m; m >>= 1) s += __shfl_xor(s, m, 64);
  if (l == 0) sc1[o] = s / 2304.0f;
  for (int tap = 0; tap < 9; ++tap) {
    int dh = tap / 3, dw = tap % 3;
    for (int jp = 0; jp < 4; ++jp) {
      int ci = jp * 64 + l;
      float wv = wo[(size_t)ci * 9 + dh * 3 + dw];
      unsigned long long m = __ballot(wv >= 0.0f);
      if (l == 0) {
        pw1[(size_t)(o * 9 + tap) * 8 + jp * 2 + 0] = (uint32_t)m;
        pw1[(size_t)(o * 9 + tap) * 8 + jp * 2 + 1] = (uint32_t)(m >> 32);
      }
    }
  }
  const float* wro = wr + (size_t)o * 256;
  float s2 = 0.f;
  for (int i = l; i < 256; i += 64) s2 += fabsf(wro[i]);
  for (int m = 32; m; m >>= 1) s2 += __shfl_xor(s2, m, 64);
  if (l == 0) sc2[o] = s2 / 256.0f;
  for (int jp = 0; jp < 4; ++jp) {
    unsigned long long m = __ballot(wro[jp * 64 + l] >= 0.0f);
    if (l == 0) {
      pw2[(size_t)o * 8 + jp * 2 + 0] = (uint32_t)m;
      pw2[(size_t)o * 8 + jp * 2 + 1] = (uint32_t)(m >> 32);
    }
  }
}

// ============ pack1: sign(x + b1_1) -> bitplanes p1[j][pg] ============
__global__ __launch_bounds__(256) void pack1_k(const float* __restrict__ x,
                                               const float* __restrict__ b1_1,
                                               uint32_t* __restrict__ p1) {
  const int j = blockIdx.y;
  const int pg = blockIdx.x * 256 + threadIdx.x;
  if (pg >= NPIX) return;
  const int n = pg / HW, p = pg % HW;
  const float* xb = x + (size_t)(n * CCH + j * 32) * HW + p;
  uint32_t w = 0;
#pragma unroll
  for (int cc = 0; cc < 32; ++cc) {
    float v = xb[(size_t)cc * HW] + b1_1[j * 32 + cc];
    w |= (v >= 0.0f ? 1u : 0u) << cc;
  }
  p1[(size_t)j * NPIX + pg] = w;
}

// ============ conv1: 3x3 binarized, popcount, + per-channel stats ============
__global__ __launch_bounds__(256) void conv1_k(const uint32_t* __restrict__ p1,
                                               const uint32_t* __restrict__ pw1,
                                               short* __restrict__ S1,
                                               long long* __restrict__ st1) {
  __shared__ uint32_t act[800];    // [r(10)][c(10)][q(8)]
  __shared__ uint32_t wt[9216];    // [ch(128)][tap(9)][q(8)]
  const int tid = threadIdx.x;
  const int tx = blockIdx.x % 7, ty = blockIdx.x / 7;
  const int n = blockIdx.y, zh = blockIdx.z;
  const int h0 = ty * 8 - 1, w0 = tx * 8 - 1;
  for (int i = tid; i < 800; i += 256) {
    int q = i / 100, rc = i % 100;
    int r = rc / 10, cl = rc % 10;
    int hh = h0 + r, ww = w0 + cl;
    uint32_t v = 0;
    if ((unsigned)hh < 56u && (unsigned)ww < 56u)
      v = p1[(size_t)q * NPIX + (size_t)n * HW + hh * 56 + ww];
    act[rc * 8 + q] = v;
  }
  const uint32_t* pwb = pw1 + (size_t)(zh * 128) * 72;
  for (int i = tid; i < 9216; i += 256) wt[i] = pwb[i];
  __syncthreads();

  const int pxg = tid & 15, chg = tid >> 4;
  const int pr = pxg >> 1, pc4 = (pxg & 1) * 4;
  const int hg = ty * 8 + pr;
  const int wbase = tx * 8 + pc4;
  int acc[4][8];
#pragma unroll
  for (int k = 0; k < 4; ++k)
#pragma unroll
    for (int cc = 0; cc < 8; ++cc) acc[k][cc] = 0;

  for (int dh = 0; dh < 3; ++dh) {
    if ((unsigned)(hg + dh - 1) >= 56u) continue;
    const int ar = pr + dh;
    for (int dw = 0; dw < 3; ++dw) {
      const int tap = dh * 3 + dw;
#pragma unroll
      for (int q = 0; q < 2; ++q) {
        uint4 a[4];
#pragma unroll
        for (int k = 0; k < 4; ++k)
          a[k] = *(const uint4*)&act[(ar * 10 + pc4 + k + dw) * 8 + q * 4];
        uint4 wv[8];
#pragma unroll
        for (int cc = 0; cc < 8; ++cc)
          wv[cc] = *(const uint4*)&wt[((chg * 8 + cc) * 9 + tap) * 8 + q * 4];
#pragma unroll
        for (int k = 0; k < 4; ++k) {
          if ((unsigned)(wbase + k + dw - 1) < 56u) {
#pragma unroll
            for (int cc = 0; cc < 8; ++cc) {
              acc[k][cc] += __builtin_popcount(a[k].x ^ wv[cc].x) +
                            __builtin_popcount(a[k].y ^ wv[cc].y) +
                            __builtin_popcount(a[k].z ^ wv[cc].z) +
                            __builtin_popcount(a[k].w ^ wv[cc].w);
            }
          }
        }
      }
    }
  }

  const int numR = 3 - (hg == 0) - (hg == 55);
  int Vk[4];
#pragma unroll
  for (int k = 0; k < 4; ++k) {
    int wg = wbase + k;
    Vk[k] = numR * (3 - (wg == 0) - (wg == 55));
  }
  const size_t srow = (size_t)(n * CCH + zh * 128 + chg * 8) * HW + hg * 56 + wbase;
  const int slot = (blockIdx.x + 49 * (blockIdx.y + 32 * blockIdx.z)) & 63;
  unsigned long long* st = (unsigned long long*)st1;
#pragma unroll
  for (int cc = 0; cc < 8; ++cc) {
    int s[4], sm = 0, sq = 0;
#pragma unroll
    for (int k = 0; k < 4; ++k) {
      s[k] = 256 * Vk[k] - 2 * acc[k][cc];
      sm += s[k];
      sq += s[k] * s[k];
    }
    short4 o4;
    o4.x = (short)s[0]; o4.y = (short)s[1]; o4.z = (short)s[2]; o4.w = (short)s[3];
    *(short4*)&S1[srow + (size_t)cc * HW] = o4;
#pragma unroll
    for (int m = 1; m < 16; m <<= 1) {
      sm += __shfl_xor(sm, m, 64);
      sq += __shfl_xor(sq, m, 64);
    }
    if ((tid & 15) == 0) {
      int c = zh * 128 + chg * 8 + cc;
      atomicAdd(&st[(size_t)(slot * 256 + c) * 2 + 0], (unsigned long long)(long long)sm);
      atomicAdd(&st[(size_t)(slot * 256 + c) * 2 + 1], (unsigned long long)(long long)sq);
    }
  }
}

// ============ BN finalize: fold to y = A*S + B ============
__global__ void bnfin_k(const long long* __restrict__ st, const float* __restrict__ sc,
                        const float* __restrict__ g, const float* __restrict__ b,
                        float* __restrict__ A, float* __restrict__ B) {
  const int c = threadIdx.x;
  long long sm = 0, sq = 0;
  for (int s = 0; s < 64; ++s) {
    sm += st[(size_t)(s * 256 + c) * 2 + 0];
    sq += st[(size_t)(s * 256 + c) * 2 + 1];
  }
  const double M = (double)NPIX;
  double mS = (double)sm / M;
  double vS = (double)sq / M - mS * mS;
  double scale = (double)sc[c];
  double mean = scale * mS;
  double var = scale * scale * vS;
  double rstd = 1.0 / sqrt(var + 1e-5);
  double gd = (double)g[c];
  A[c] = (float)(gd * scale * rstd);
  B[c] = (float)((double)b[c] - gd * mean * rstd);
}

// ============ pack2: elementwise chain -> sign bits p2[j][pg] ============
__global__ __launch_bounds__(256) void pack2_k(const float* __restrict__ x,
    const short* __restrict__ S1,
    const float* __restrict__ A1, const float* __restrict__ B1,
    const float* __restrict__ b1_2, const float* __restrict__ a1,
    const float* __restrict__ b1_3, const float* __restrict__ b2_1,
    uint32_t* __restrict__ p2) {
  const int j = blockIdx.y;
  const int pg = blockIdx.x * 256 + threadIdx.x;
  if (pg >= NPIX) return;
  const int n = pg / HW, p = pg % HW;
  const size_t base = (size_t)(n * CCH + j * 32) * HW + p;
  uint32_t wd = 0;
#pragma unroll
  for (int cc = 0; cc < 32; ++cc) {
    int c = j * 32 + cc;
    size_t idx = base + (size_t)cc * HW;
    float y = A1[c] * (float)S1[idx] + B1[c];
    float u = x[idx] + y;
    u = u + b1_2[c];
    float v = u >= 0.0f ? u : a1[c] * u;
    float t = v + b1_3[c];
    wd |= ((t + b2_1[c]) >= 0.0f ? 1u : 0u) << cc;
  }
  p2[(size_t)j * NPIX + pg] = wd;
}

// ============ conv2: 1x1 binarized, popcount, + stats ============
__global__ __launch_bounds__(256) void conv2_k(const uint32_t* __restrict__ p2,
                                               const uint32_t* __restrict__ pw2,
                                               short* __restrict__ S2,
                                               long long* __restrict__ st2) {
  __shared__ uint32_t act[512];   // [px(64)][q(8)]
  __shared__ uint32_t wt[1024];   // [ch(128)][q(8)]
  const int tid = threadIdx.x;
  const int pg0 = blockIdx.x * 64;
  const int zh = blockIdx.y;
  for (int i = tid; i < 512; i += 256) {
    int q = i >> 6, px = i & 63;
    act[px * 8 + q] = p2[(size_t)q * NPIX + pg0 + px];
  }
  for (int i = tid; i < 1024; i += 256) wt[i] = pw2[(size_t)zh * 1024 + i];
  __syncthreads();
  const int pxg = tid & 15, chg = tid >> 4;
  int acc[4][8];
#pragma unroll
  for (int k = 0; k < 4; ++k)
#pragma unroll
    for (int cc = 0; cc < 8; ++cc) acc[k][cc] = 0;
#pragma unroll
  for (int q = 0; q < 2; ++q) {
    uint4 a[4];
#pragma unroll
    for (int k = 0; k < 4; ++k)
      a[k] = *(const uint4*)&act[(pxg * 4 + k) * 8 + q * 4];
    uint4 wv[8];
#pragma unroll
    for (int cc = 0; cc < 8; ++cc)
      wv[cc] = *(const uint4*)&wt[(chg * 8 + cc) * 8 + q * 4];
#pragma unroll
    for (int k = 0; k < 4; ++k)
#pragma unroll
      for (int cc = 0; cc < 8; ++cc)
        acc[k][cc] += __builtin_popcount(a[k].x ^ wv[cc].x) +
                      __builtin_popcount(a[k].y ^ wv[cc].y) +
                      __builtin_popcount(a[k].z ^ wv[cc].z) +
                      __builtin_popcount(a[k].w ^ wv[cc].w);
  }
  const int pg = pg0 + pxg * 4;            // 64 | 3136 -> never crosses image
  const int n = pg / HW, p = pg % HW;
  const size_t srow = (size_t)(n * CCH + zh * 128 + chg * 8) * HW + p;
  const int slot = blockIdx.x & 63;
  unsigned long long* st = (unsigned long long*)st2;
#pragma unroll
  for (int cc = 0; cc < 8; ++cc) {
    int s[4], sm = 0, sq = 0;
#pragma unroll
    for (int k = 0; k < 4; ++k) {
      s[k] = 256 - 2 * acc[k][cc];
      sm += s[k];
      sq += s[k] * s[k];
    }
    short4 o4;
    o4.x = (short)s[0]; o4.y = (short)s[1]; o4.z = (short)s[2]; o4.w = (short)s[3];
    *(short4*)&S2[srow + (size_t)cc * HW] = o4;
#pragma unroll
    for (int m = 1; m < 16; m <<= 1) {
      sm += __shfl_xor(sm, m, 64);
      sq += __shfl_xor(sq, m, 64);
    }
    if ((tid & 15) == 0) {
      int c = zh * 128 + chg * 8 + cc;
      atomicAdd(&st[(size_t)(slot * 256 + c) * 2 + 0], (unsigned long long)(long long)sm);
      atomicAdd(&st[(size_t)(slot * 256 + c) * 2 + 1], (unsigned long long)(long long)sq);
    }
  }
}

// ============ final: recompute t, BN2 + residual + PReLU chain ============
__global__ __launch_bounds__(256) void final_k(const float* __restrict__ x,
    const short* __restrict__ S1, const short* __restrict__ S2,
    const float* __restrict__ A1, const float* __restrict__ B1,
    const float* __restrict__ b1_2, const float* __restrict__ a1, const float* __restrict__ b1_3,
    const float* __restrict__ A2, const float* __restrict__ B2,
    const float* __restrict__ b2_2, const float* __restrict__ a2, const float* __restrict__ b2_3,
    float* __restrict__ out) {
  const size_t i = ((size_t)blockIdx.x * 256 + threadIdx.x) * 4;
  const int c = (int)((i / HW) & 255);
  float4 xv = *(const float4*)(x + i);
  short4 s1 = *(const short4*)(S1 + i);
  short4 s2 = *(const short4*)(S2 + i);
  const float A1c = A1[c], B1c = B1[c], P12 = b1_2[c], AL1 = a1[c], P13 = b1_3[c];
  const float A2c = A2[c], B2c = B2[c], P22 = b2_2[c], AL2 = a2[c], P23 = b2_3[c];
  float xs[4] = {xv.x, xv.y, xv.z, xv.w};
  float f1[4] = {(float)s1.x, (float)s1.y, (float)s1.z, (float)s1.w};
  float f2[4] = {(float)s2.x, (float)s2.y, (float)s2.z, (float)s2.w};
  float o[4];
#pragma unroll
  for (int e = 0; e < 4; ++e) {
    float u = xs[e] + (A1c * f1[e] + B1c);
    u = u + P12;
    float v = u >= 0.0f ? u : AL1 * u;
    float t = v + P13;
    float z = (A2c * f2[e] + B2c) + t;
    z = z + P22;
    float vv = z >= 0.0f ? z : AL2 * z;
    o[e] = vv + P23;
  }
  float4 ov = {o[0], o[1], o[2], o[3]};
  *(float4*)(out + i) = ov;
}

extern "C" void kernel_launch(void* const* d_in, const int* in_sizes, int n_in,
                              void* d_out, int out_size, void* d_ws, size_t ws_size,
                              hipStream_t stream) {
  const float* x    = (const float*)d_in[0];
  const float* b1_1 = (const float*)d_in[1];
  const float* w3x3 = (const float*)d_in[2];
  const float* bn1g = (const float*)d_in[3];
  const float* bn1b = (const float*)d_in[4];
  const float* b1_2 = (const float*)d_in[5];
  const float* a1   = (const float*)d_in[6];
  const float* b1_3 = (const float*)d_in[7];
  const float* b2_1 = (const float*)d_in[8];
  const float* wres = (const float*)d_in[9];
  const float* bn2g = (const float*)d_in[10];
  const float* bn2b = (const float*)d_in[11];
  const float* b2_2 = (const float*)d_in[12];
  const float* a2   = (const float*)d_in[13];
  const float* b2_3 = (const float*)d_in[14];

  char* ws = (char*)d_ws;
  uint32_t* pw1 = (uint32_t*)(ws + OFF_PW1);
  uint32_t* pw2 = (uint32_t*)(ws + OFF_PW2);
  float* sc1 = (float*)(ws + OFF_SC1);
  float* sc2 = (float*)(ws + OFF_SC2);
  float* A1 = (float*)(ws + OFF_A1);
  float* B1 = (float*)(ws + OFF_B1);
  float* A2 = (float*)(ws + OFF_A2);
  float* B2 = (float*)(ws + OFF_B2);
  long long* st1 = (long long*)(ws + OFF_ST);
  long long* st2 = (long long*)(ws + OFF_ST + 262144u);
  uint32_t* p1 = (uint32_t*)(ws + OFF_P1);
  uint32_t* p2 = (uint32_t*)(ws + OFF_P2);
  short* S1 = (short*)(ws + OFF_S1);
  short* S2 = (short*)(ws + OFF_S2);

  hipMemsetAsync(ws + OFF_ST, 0, ST_BYTES, stream);
  prep_w_k<<<256, 64, 0, stream>>>(w3x3, wres, pw1, pw2, sc1, sc2);
  pack1_k<<<dim3(392, 8), 256, 0, stream>>>(x, b1_1, p1);
  conv1_k<<<dim3(49, 32, 2), 256, 0, stream>>>(p1, pw1, S1, st1);
  bnfin_k<<<1, 256, 0, stream>>>(st1, sc1, bn1g, bn1b, A1, B1);
  pack2_k<<<dim3(392, 8), 256, 0, stream>>>(x, S1, A1, B1, b1_2, a1, b1_3, b2_1, p2);
  conv2_k<<<dim3(1568, 2), 256, 0, stream>>>(p2, pw2, S2, st2);
  bnfin_k<<<1, 256, 0, stream>>>(st2, sc2, bn2g, bn2b, A2, B2);
  final_k<<<25088, 256, 0, stream>>>(x, S1, S2, A1, B1, b1_2, a1, b1_3,
                                     A2, B2, b2_2, a2, b2_3, (float*)d_out);
}

// Round 2
// 508.491 us; speedup vs baseline: 1.0337x; 1.0337x over previous
//
#include <hip/hip_runtime.h>
#include <cstdint>
#include <math.h>

#define HW    3136
#define NPIX  100352      // 32*3136
#define NELEM 25690112    // 32*256*3136

// ---- workspace layout (byte offsets) ----
#define OFF_PW1   0u           // 256*9*8 u32 = 73728
#define OFF_PW2   73728u       // 256*8 u32   = 8192
#define OFF_CORR  81920u       // 256*8 i16   = 4096
#define OFF_SC1   86016u
#define OFF_SC2   87040u
#define OFF_A1    88064u
#define OFF_B1    89088u
#define OFF_A2    90112u
#define OFF_B2    91136u
#define OFF_ST    92160u       // st1: 256ch*64slot*2 ull = 262144 ; st2 follows
#define ST_BYTES  524288u
#define OFF_P1    616448u      // NPIX*8 u32 = 3211264
#define OFF_P2    3827712u
#define OFF_S1    7038976u     // NELEM i16 (tiled) = 51380224
#define OFF_S2    58419200u    // NELEM i16 (tiled)

// ============ weight prep: scales + packing + edge-correction table ============
__global__ void prep_w_k(const float* __restrict__ w3, const float* __restrict__ wr,
                         uint32_t* __restrict__ pw1, uint32_t* __restrict__ pw2,
                         float* __restrict__ sc1, float* __restrict__ sc2,
                         short* __restrict__ corrG) {
  const int o = blockIdx.x, l = threadIdx.x;   // 64 threads = 1 wave
  const float* wo = w3 + (size_t)o * 2304;
  float s = 0.f;
  for (int i = l; i < 2304; i += 64) s += fabsf(wo[i]);
  for (int m = 32; m; m >>= 1) s += __shfl_xor(s, m, 64);
  if (l == 0) sc1[o] = s / 2304.0f;
  int wsum[9];
  for (int tap = 0; tap < 9; ++tap) {
    int cnt = 0;
    for (int jp = 0; jp < 4; ++jp) {
      float wv = wo[(size_t)(jp * 64 + l) * 9 + tap];
      unsigned long long m = __ballot(wv >= 0.0f);
      cnt += __popcll(m);
      if (l == 0) {
        pw1[(size_t)(o * 9 + tap) * 8 + jp * 2 + 0] = (uint32_t)m;
        pw1[(size_t)(o * 9 + tap) * 8 + jp * 2 + 1] = (uint32_t)(m >> 32);
      }
    }
    wsum[tap] = 2 * cnt - 256;   // sum of +-1 weights for this tap
  }
  if (l == 0) {
    // [R0, R2, C0, C2, w00, w02, w20, w22]
    corrG[o * 8 + 0] = (short)(wsum[0] + wsum[1] + wsum[2]);
    corrG[o * 8 + 1] = (short)(wsum[6] + wsum[7] + wsum[8]);
    corrG[o * 8 + 2] = (short)(wsum[0] + wsum[3] + wsum[6]);
    corrG[o * 8 + 3] = (short)(wsum[2] + wsum[5] + wsum[8]);
    corrG[o * 8 + 4] = (short)wsum[0];
    corrG[o * 8 + 5] = (short)wsum[2];
    corrG[o * 8 + 6] = (short)wsum[6];
    corrG[o * 8 + 7] = (short)wsum[8];
  }
  const float* wro = wr + (size_t)o * 256;
  float s2 = 0.f;
  for (int i = l; i < 256; i += 64) s2 += fabsf(wro[i]);
  for (int m = 32; m; m >>= 1) s2 += __shfl_xor(s2, m, 64);
  if (l == 0) sc2[o] = s2 / 256.0f;
  for (int jp = 0; jp < 4; ++jp) {
    unsigned long long m = __ballot(wro[jp * 64 + l] >= 0.0f);
    if (l == 0) {
      pw2[(size_t)o * 8 + jp * 2 + 0] = (uint32_t)m;
      pw2[(size_t)o * 8 + jp * 2 + 1] = (uint32_t)(m >> 32);
    }
  }
}

// ============ pack1: sign(x + b1_1) -> bitplanes, float4-vectorized ============
__global__ __launch_bounds__(256) void pack1_k(const float* __restrict__ x,
                                               const float* __restrict__ b1_1,
                                               uint32_t* __restrict__ p1) {
  const int j = blockIdx.y;
  const int gpx = blockIdx.x * 256 + threadIdx.x;   // 0..25087 (px groups of 4)
  const int n = gpx / 784;
  const int p4 = (gpx - n * 784) * 4;
  const float* xb = x + ((size_t)n * 256 + j * 32) * HW + p4;
  uint32_t w0 = 0, w1 = 0, w2 = 0, w3 = 0;
#pragma unroll
  for (int cc = 0; cc < 32; ++cc) {
    float4 v = *(const float4*)(xb + (size_t)cc * HW);
    float bb = b1_1[j * 32 + cc];
    w0 |= (v.x + bb >= 0.f) ? (1u << cc) : 0u;
    w1 |= (v.y + bb >= 0.f) ? (1u << cc) : 0u;
    w2 |= (v.z + bb >= 0.f) ? (1u << cc) : 0u;
    w3 |= (v.w + bb >= 0.f) ? (1u << cc) : 0u;
  }
  uint4 o = {w0, w1, w2, w3};
  *(uint4*)&p1[(size_t)j * NPIX + gpx * 4] = o;
}

// ============ conv1: 3x3 binarized, branch-free, 8px x 8ch per thread ============
// block: 256 thr = 4 waves; tile 8x8 px, 2 images, 128 ch (zh half)
// lane: chg = tid&7, pr = (tid>>3)&7 ; wave: img = wave>>1, chalf = wave&1
// thread channels: ch_l = chalf*8 + chg + 16*j  (j 0..7)  -> LDS w-reads conflict-free
__global__ __launch_bounds__(256, 3) void conv1_k(const uint32_t* __restrict__ p1,
    const uint32_t* __restrict__ pw1, const short* __restrict__ corrG,
    short* __restrict__ S1, unsigned long long* __restrict__ st1) {
  __shared__ uint32_t actS[1680];   // 2 img x 10 rows x stride 84 (10 cols x 8q + 4 pad)
  __shared__ uint32_t wtS[9216];    // [ch_l 128][tap 9][q 8]
  __shared__ short    corrS[1024];  // [ch_l 128][8]
  const int tid = threadIdx.x;
  const int bx = blockIdx.x;            // 0..48 tile
  const int ty = bx / 7, tx = bx % 7;
  const int by = blockIdx.y;            // 0..15 img pair
  const int zh = blockIdx.z;            // 0..1 ch half
  const int h0 = ty * 8 - 1, w0 = tx * 8 - 1;
  for (int i = tid; i < 1600; i += 256) {
    int img = i / 800, rem = i % 800;
    int r = rem / 80, c = (rem % 80) / 8, q = i & 7;
    int hh = h0 + r, ww = w0 + c;
    uint32_t v = 0;
    if ((unsigned)hh < 56u && (unsigned)ww < 56u)
      v = p1[q * NPIX + (by * 2 + img) * HW + hh * 56 + ww];
    actS[img * 840 + r * 84 + c * 8 + q] = v;
  }
  for (int i = tid; i < 2304; i += 256)
    ((uint4*)wtS)[i] = ((const uint4*)(pw1 + (size_t)zh * 9216))[i];
  if (tid < 128)
    ((uint4*)corrS)[tid] = ((const uint4*)(corrG + zh * 1024))[tid];
  __syncthreads();

  const int chg = tid & 7;
  const int pr = (tid >> 3) & 7;
  const int wave = tid >> 6;
  const int img = wave >> 1;
  const int chalf = wave & 1;
  const int cb = chalf * 8 + chg;
  const uint32_t* actB = actS + img * 840;

  int acc[8][8];
#pragma unroll
  for (int j = 0; j < 8; ++j)
#pragma unroll
    for (int k = 0; k < 8; ++k) acc[j][k] = 0;

#pragma unroll 1
  for (int dh = 0; dh < 3; ++dh) {
#pragma unroll 1
    for (int q4 = 0; q4 < 2; ++q4) {
      uint4 a10[10];
      const uint32_t* ar = actB + (pr + dh) * 84 + q4 * 4;
#pragma unroll
      for (int c2 = 0; c2 < 10; ++c2) a10[c2] = *(const uint4*)(ar + c2 * 8);
#pragma unroll
      for (int dw = 0; dw < 3; ++dw) {
        const uint32_t* wr_ = wtS + cb * 72 + (dh * 3 + dw) * 8 + q4 * 4;
#pragma unroll
        for (int j = 0; j < 8; ++j) {
          uint4 w = *(const uint4*)(wr_ + j * 1152);   // j*16*72
#pragma unroll
          for (int k = 0; k < 8; ++k) {
            uint4 a = a10[k + dw];
            acc[j][k] += __builtin_popcount(a.x ^ w.x) + __builtin_popcount(a.y ^ w.y)
                       + __builtin_popcount(a.z ^ w.z) + __builtin_popcount(a.w ^ w.w);
          }
        }
      }
    }
  }

  const int n = by * 2 + img;
  const int h = ty * 8 + pr;
  const bool hT = (h == 0), hB = (h == 55);
  const int slot = (bx + by * 49 + zh * 784) & 63;
#pragma unroll
  for (int j = 0; j < 8; ++j) {
    const int ch_l = cb + 16 * j;
    const short* cw = &corrS[ch_l * 8];
    int cH = hT ? (int)cw[0] : (hB ? (int)cw[1] : 0);
    int s[8];
#pragma unroll
    for (int k = 0; k < 8; ++k) s[k] = 2304 - 2 * acc[j][k] + cH;
    if (tx == 0) s[0] += (int)cw[2] - (hT ? (int)cw[4] : (hB ? (int)cw[6] : 0));
    if (tx == 6) s[7] += (int)cw[3] - (hT ? (int)cw[5] : (hB ? (int)cw[7] : 0));
    int sm = 0, sq = 0;
#pragma unroll
    for (int k = 0; k < 8; ++k) { sm += s[k]; sq += s[k] * s[k]; }
    uint4 val;
    val.x = (uint32_t)(uint16_t)s[0] | ((uint32_t)(uint16_t)s[1] << 16);
    val.y = (uint32_t)(uint16_t)s[2] | ((uint32_t)(uint16_t)s[3] << 16);
    val.z = (uint32_t)(uint16_t)s[4] | ((uint32_t)(uint16_t)s[5] << 16);
    val.w = (uint32_t)(uint16_t)s[6] | ((uint32_t)(uint16_t)s[7] << 16);
    *(uint4*)&S1[(((size_t)n * 49 + bx) * 256 + zh * 128 + ch_l) * 64 + pr * 8] = val;
#pragma unroll
    for (int m = 8; m < 64; m <<= 1) { sm += __shfl_xor(sm, m, 64); sq += __shfl_xor(sq, m, 64); }
    if (pr == 0) {
      unsigned long long* st = st1 + ((size_t)(zh * 128 + ch_l) * 64 + slot) * 2;
      atomicAdd(&st[0], (unsigned long long)(long long)sm);
      atomicAdd(&st[1], (unsigned long long)(long long)sq);
    }
  }
}

// ============ BN finalize (parallel): fold to y = A*S + B ============
__global__ void bnfin_k(const unsigned long long* __restrict__ st, const float* __restrict__ sc,
                        const float* __restrict__ g, const float* __restrict__ b,
                        float* __restrict__ A, float* __restrict__ B) {
  const int c = blockIdx.x, l = threadIdx.x;
  long long sm = (long long)st[((size_t)c * 64 + l) * 2 + 0];
  long long sq = (long long)st[((size_t)c * 64 + l) * 2 + 1];
  for (int m = 1; m < 64; m <<= 1) { sm += __shfl_xor(sm, m, 64); sq += __shfl_xor(sq, m, 64); }
  if (l == 0) {
    const double M = (double)NPIX;
    double mS = (double)sm / M;
    double vS = (double)sq / M - mS * mS;
    double scale = (double)sc[c];
    double mean = scale * mS;
    double var = scale * scale * vS;
    double rstd = 1.0 / sqrt(var + 1e-5);
    double gd = (double)g[c];
    A[c] = (float)(gd * scale * rstd);
    B[c] = (float)((double)b[c] - gd * mean * rstd);
  }
}

// ============ pack2: elementwise chain -> sign bits, float4-vectorized ============
__global__ __launch_bounds__(256) void pack2_k(const float* __restrict__ x,
    const short* __restrict__ S1,
    const float* __restrict__ A1, const float* __restrict__ B1,
    const float* __restrict__ b1_2, const float* __restrict__ a1,
    const float* __restrict__ b1_3, const float* __restrict__ b2_1,
    uint32_t* __restrict__ p2) {
  const int j = blockIdx.y;
  const int gpx = blockIdx.x * 256 + threadIdx.x;
  const int n = gpx / 784;
  const int p4 = (gpx - n * 784) * 4;
  const int h = p4 / 56, w = p4 - (p4 / 56) * 56;
  const int tile = (h >> 3) * 7 + (w >> 3);
  const int px = (h & 7) * 8 + (w & 7);
  const float* xb = x + ((size_t)n * 256 + j * 32) * HW + p4;
  const short* s1b = S1 + (((size_t)n * 49 + tile) * 256 + j * 32) * 64 + px;
  uint32_t w0 = 0, w1 = 0, w2 = 0, w3 = 0;
#pragma unroll
  for (int cc = 0; cc < 32; ++cc) {
    int c = j * 32 + cc;
    float4 xv = *(const float4*)(xb + (size_t)cc * HW);
    short4 s1 = *(const short4*)(s1b + cc * 64);
    float Ac = A1[c], Bc = B1[c], p12 = b1_2[c], al = a1[c], p13 = b1_3[c], p21 = b2_1[c];
    float u, v, t;
    u = xv.x + (Ac * (float)s1.x + Bc) + p12; v = u >= 0.f ? u : al * u; t = v + p13 + p21;
    w0 |= (t >= 0.f) ? (1u << cc) : 0u;
    u = xv.y + (Ac * (float)s1.y + Bc) + p12; v = u >= 0.f ? u : al * u; t = v + p13 + p21;
    w1 |= (t >= 0.f) ? (1u << cc) : 0u;
    u = xv.z + (Ac * (float)s1.z + Bc) + p12; v = u >= 0.f ? u : al * u; t = v + p13 + p21;
    w2 |= (t >= 0.f) ? (1u << cc) : 0u;
    u = xv.w + (Ac * (float)s1.w + Bc) + p12; v = u >= 0.f ? u : al * u; t = v + p13 + p21;
    w3 |= (t >= 0.f) ? (1u << cc) : 0u;
  }
  uint4 o = {w0, w1, w2, w3};
  *(uint4*)&p2[(size_t)j * NPIX + gpx * 4] = o;
}

// ============ conv2: 1x1 binarized, swizzled act, interleaved channels ============
__global__ __launch_bounds__(256) void conv2_k(const uint32_t* __restrict__ p2,
                                               const uint32_t* __restrict__ pw2,
                                               short* __restrict__ S2,
                                               unsigned long long* __restrict__ st2) {
  __shared__ uint32_t actS[512];   // 64 px x 8 q, XOR-swizzled 16B groups
  __shared__ uint32_t wtS[1024];   // [ch_l 128][q 8]
  const int tid = threadIdx.x;
  const int bx = blockIdx.x;       // 0..1567 pixel group
  const int zh = blockIdx.y;
  const int pg0 = bx * 64;
  for (int i = tid; i < 512; i += 256) {
    int gq = i >> 2, ws_ = i & 3;
    int pxl = gq >> 1, q4 = gq & 1;
    int q = q4 * 4 + ws_;
    actS[((gq ^ ((gq >> 3) & 15)) << 2) + ws_] = p2[q * NPIX + pg0 + pxl];
  }
  if (tid < 256)
    ((uint4*)wtS)[tid] = ((const uint4*)(pw2 + zh * 1024))[tid];
  __syncthreads();
  const int pxg = tid & 15, chg = tid >> 4;
  int acc[8][4];
#pragma unroll
  for (int j = 0; j < 8; ++j)
#pragma unroll
    for (int k = 0; k < 4; ++k) acc[j][k] = 0;
#pragma unroll
  for (int q4 = 0; q4 < 2; ++q4) {
    uint4 a[4];
#pragma unroll
    for (int k = 0; k < 4; ++k) {
      int gq = 8 * pxg + 2 * k + q4;
      a[k] = *(const uint4*)&actS[(gq ^ pxg) << 2];
    }
#pragma unroll
    for (int j = 0; j < 8; ++j) {
      uint4 w = *(const uint4*)&wtS[(chg + 16 * j) * 8 + q4 * 4];
#pragma unroll
      for (int k = 0; k < 4; ++k)
        acc[j][k] += __builtin_popcount(a[k].x ^ w.x) + __builtin_popcount(a[k].y ^ w.y)
                   + __builtin_popcount(a[k].z ^ w.z) + __builtin_popcount(a[k].w ^ w.w);
    }
  }
  const int slot = bx & 63;
#pragma unroll
  for (int j = 0; j < 8; ++j) {
    const int c_l = chg + 16 * j;
    int s[4], sm = 0, sq = 0;
#pragma unroll
    for (int k = 0; k < 4; ++k) {
      s[k] = 256 - 2 * acc[j][k];
      sm += s[k]; sq += s[k] * s[k];
    }
    short4 o4;
    o4.x = (short)s[0]; o4.y = (short)s[1]; o4.z = (short)s[2]; o4.w = (short)s[3];
    *(short4*)&S2[(((size_t)bx * 256) + zh * 128 + c_l) * 64 + pxg * 4] = o4;
#pragma unroll
    for (int m = 1; m < 16; m <<= 1) { sm += __shfl_xor(sm, m, 64); sq += __shfl_xor(sq, m, 64); }
    if (pxg == 0) {
      unsigned long long* st = st2 + ((size_t)(zh * 128 + c_l) * 64 + slot) * 2;
      atomicAdd(&st[0], (unsigned long long)(long long)sm);
      atomicAdd(&st[1], (unsigned long long)(long long)sq);
    }
  }
}

// ============ final: recompute t, BN2 + residual + PReLU chain ============
__global__ __launch_bounds__(256) void final_k(const float* __restrict__ x,
    const short* __restrict__ S1, const short* __restrict__ S2,
    const float* __restrict__ A1, const float* __restrict__ B1,
    const float* __restrict__ b1_2, const float* __restrict__ a1, const float* __restrict__ b1_3,
    const float* __restrict__ A2, const float* __restrict__ B2,
    const float* __restrict__ b2_2, const float* __restrict__ a2, const float* __restrict__ b2_3,
    float* __restrict__ out) {
  const int gi = blockIdx.x * 256 + threadIdx.x;
  const int i4 = gi * 4;
  const int nc = i4 / 3136;
  const int p = i4 - nc * 3136;
  const int n = nc >> 8, c = nc & 255;
  const int h = p / 56, w = p - (p / 56) * 56;
  const int tile = (h >> 3) * 7 + (w >> 3);
  const int px = (h & 7) * 8 + (w & 7);
  short4 s1 = *(const short4*)&S1[(((size_t)n * 49 + tile) * 256 + c) * 64 + px];
  const int pg = n * 3136 + p;
  short4 s2 = *(const short4*)&S2[((size_t)(pg >> 6) * 256 + c) * 64 + (pg & 63)];
  float4 xv = *(const float4*)&x[i4];
  const float A1c = A1[c], B1c = B1[c], P12 = b1_2[c], AL1 = a1[c], P13 = b1_3[c];
  const float A2c = A2[c], B2c = B2[c], P22 = b2_2[c], AL2 = a2[c], P23 = b2_3[c];
  float xs[4] = {xv.x, xv.y, xv.z, xv.w};
  float f1[4] = {(float)s1.x, (float)s1.y, (float)s1.z, (float)s1.w};
  float f2[4] = {(float)s2.x, (float)s2.y, (float)s2.z, (float)s2.w};
  float o[4];
#pragma unroll
  for (int e = 0; e < 4; ++e) {
    float u = xs[e] + (A1c * f1[e] + B1c);
    u = u + P12;
    float v = u >= 0.0f ? u : AL1 * u;
    float t = v + P13;
    float z = (A2c * f2[e] + B2c) + t;
    z = z + P22;
    float vv = z >= 0.0f ? z : AL2 * z;
    o[e] = vv + P23;
  }
  float4 ov = {o[0], o[1], o[2], o[3]};
  *(float4*)&out[i4] = ov;
}

extern "C" void kernel_launch(void* const* d_in, const int* in_sizes, int n_in,
                              void* d_out, int out_size, void* d_ws, size_t ws_size,
                              hipStream_t stream) {
  const float* x    = (const float*)d_in[0];
  const float* b1_1 = (const float*)d_in[1];
  const float* w3x3 = (const float*)d_in[2];
  const float* bn1g = (const float*)d_in[3];
  const float* bn1b = (const float*)d_in[4];
  const float* b1_2 = (const float*)d_in[5];
  const float* a1   = (const float*)d_in[6];
  const float* b1_3 = (const float*)d_in[7];
  const float* b2_1 = (const float*)d_in[8];
  const float* wres = (const float*)d_in[9];
  const float* bn2g = (const float*)d_in[10];
  const float* bn2b = (const float*)d_in[11];
  const float* b2_2 = (const float*)d_in[12];
  const float* a2   = (const float*)d_in[13];
  const float* b2_3 = (const float*)d_in[14];

  char* ws = (char*)d_ws;
  uint32_t* pw1 = (uint32_t*)(ws + OFF_PW1);
  uint32_t* pw2 = (uint32_t*)(ws + OFF_PW2);
  short* corrG = (short*)(ws + OFF_CORR);
  float* sc1 = (float*)(ws + OFF_SC1);
  float* sc2 = (float*)(ws + OFF_SC2);
  float* A1 = (float*)(ws + OFF_A1);
  float* B1 = (float*)(ws + OFF_B1);
  float* A2 = (float*)(ws + OFF_A2);
  float* B2 = (float*)(ws + OFF_B2);
  unsigned long long* st1 = (unsigned long long*)(ws + OFF_ST);
  unsigned long long* st2 = (unsigned long long*)(ws + OFF_ST + 262144u);
  uint32_t* p1 = (uint32_t*)(ws + OFF_P1);
  uint32_t* p2 = (uint32_t*)(ws + OFF_P2);
  short* S1 = (short*)(ws + OFF_S1);
  short* S2 = (short*)(ws + OFF_S2);

  hipMemsetAsync(ws + OFF_ST, 0, ST_BYTES, stream);
  prep_w_k<<<256, 64, 0, stream>>>(w3x3, wres, pw1, pw2, sc1, sc2, corrG);
  pack1_k<<<dim3(98, 8), 256, 0, stream>>>(x, b1_1, p1);
  conv1_k<<<dim3(49, 16, 2), 256, 0, stream>>>(p1, pw1, corrG, S1, st1);
  bnfin_k<<<256, 64, 0, stream>>>(st1, sc1, bn1g, bn1b, A1, B1);
  pack2_k<<<dim3(98, 8), 256, 0, stream>>>(x, S1, A1, B1, b1_2, a1, b1_3, b2_1, p2);
  conv2_k<<<dim3(1568, 2), 256, 0, stream>>>(p2, pw2, S2, st2);
  bnfin_k<<<256, 64, 0, stream>>>(st2, sc2, bn2g, bn2b, A2, B2);
  final_k<<<25088, 256, 0, stream>>>(x, S1, S2, A1, B1, b1_2, a1, b1_3,
                                     A2, B2, b2_2, a2, b2_3, (float*)d_out);
}

// Round 3
// 500.810 us; speedup vs baseline: 1.0496x; 1.0153x over previous
//
#include <hip/hip_runtime.h>
#include <cstdint>
#include <math.h>

#define HW    3136
#define NPIX  100352      // 32*3136
#define NELEM 25690112    // 32*256*3136

// ---- workspace layout (byte offsets) ----
#define OFF_PW1   0u           // 256*9*8 u32 = 73728
#define OFF_PW2   73728u       // 256*8 u32   = 8192
#define OFF_CORR  81920u       // 256*8 i16   = 4096
#define OFF_SC1   86016u
#define OFF_SC2   87040u
#define OFF_A1    88064u
#define OFF_B1    89088u
#define OFF_A2    90112u
#define OFF_B2    91136u
#define OFF_ST    92160u       // st1: 256ch*64slot*2 ull = 262144 ; st2 follows
#define ST_BYTES  524288u
#define OFF_P1    616448u      // NPIX*8 u32 = 3211264
#define OFF_P2    3827712u
#define OFF_S1    7038976u     // NELEM i16 (tiled) = 51380224
#define OFF_S2    58419200u    // NELEM i16 (tiled)

// ============ weight prep: scales + packing + edge-correction table ============
__global__ void prep_w_k(const float* __restrict__ w3, const float* __restrict__ wr,
                         uint32_t* __restrict__ pw1, uint32_t* __restrict__ pw2,
                         float* __restrict__ sc1, float* __restrict__ sc2,
                         short* __restrict__ corrG) {
  const int o = blockIdx.x, l = threadIdx.x;   // 64 threads = 1 wave
  const float* wo = w3 + (size_t)o * 2304;
  float s = 0.f;
  for (int i = l; i < 2304; i += 64) s += fabsf(wo[i]);
  for (int m = 32; m; m >>= 1) s += __shfl_xor(s, m, 64);
  if (l == 0) sc1[o] = s / 2304.0f;
  int wsum[9];
  for (int tap = 0; tap < 9; ++tap) {
    int cnt = 0;
    for (int jp = 0; jp < 4; ++jp) {
      float wv = wo[(size_t)(jp * 64 + l) * 9 + tap];
      unsigned long long m = __ballot(wv >= 0.0f);
      cnt += __popcll(m);
      if (l == 0) {
        pw1[(size_t)(o * 9 + tap) * 8 + jp * 2 + 0] = (uint32_t)m;
        pw1[(size_t)(o * 9 + tap) * 8 + jp * 2 + 1] = (uint32_t)(m >> 32);
      }
    }
    wsum[tap] = 2 * cnt - 256;   // sum of +-1 weights for this tap
  }
  if (l == 0) {
    // [R0, R2, C0, C2, w00, w02, w20, w22]
    corrG[o * 8 + 0] = (short)(wsum[0] + wsum[1] + wsum[2]);
    corrG[o * 8 + 1] = (short)(wsum[6] + wsum[7] + wsum[8]);
    corrG[o * 8 + 2] = (short)(wsum[0] + wsum[3] + wsum[6]);
    corrG[o * 8 + 3] = (short)(wsum[2] + wsum[5] + wsum[8]);
    corrG[o * 8 + 4] = (short)wsum[0];
    corrG[o * 8 + 5] = (short)wsum[2];
    corrG[o * 8 + 6] = (short)wsum[6];
    corrG[o * 8 + 7] = (short)wsum[8];
  }
  const float* wro = wr + (size_t)o * 256;
  float s2 = 0.f;
  for (int i = l; i < 256; i += 64) s2 += fabsf(wro[i]);
  for (int m = 32; m; m >>= 1) s2 += __shfl_xor(s2, m, 64);
  if (l == 0) sc2[o] = s2 / 256.0f;
  for (int jp = 0; jp < 4; ++jp) {
    unsigned long long m = __ballot(wro[jp * 64 + l] >= 0.0f);
    if (l == 0) {
      pw2[(size_t)o * 8 + jp * 2 + 0] = (uint32_t)m;
      pw2[(size_t)o * 8 + jp * 2 + 1] = (uint32_t)(m >> 32);
    }
  }
}

// ============ pack1: sign(x + b1_1) -> bitplanes, float4-vectorized ============
__global__ __launch_bounds__(256) void pack1_k(const float* __restrict__ x,
                                               const float* __restrict__ b1_1,
                                               uint32_t* __restrict__ p1) {
  const int j = blockIdx.y;
  const int gpx = blockIdx.x * 256 + threadIdx.x;   // 0..25087 (px groups of 4)
  const int n = gpx / 784;
  const int p4 = (gpx - n * 784) * 4;
  const float* xb = x + ((size_t)n * 256 + j * 32) * HW + p4;
  uint32_t w0 = 0, w1 = 0, w2 = 0, w3 = 0;
#pragma unroll
  for (int cc = 0; cc < 32; ++cc) {
    float4 v = *(const float4*)(xb + (size_t)cc * HW);
    float bb = b1_1[j * 32 + cc];
    w0 |= (v.x + bb >= 0.f) ? (1u << cc) : 0u;
    w1 |= (v.y + bb >= 0.f) ? (1u << cc) : 0u;
    w2 |= (v.z + bb >= 0.f) ? (1u << cc) : 0u;
    w3 |= (v.w + bb >= 0.f) ? (1u << cc) : 0u;
  }
  uint4 o = {w0, w1, w2, w3};
  *(uint4*)&p1[(size_t)j * NPIX + gpx * 4] = o;
}

// ============ conv1: 3x3 binarized, 8px x 4ch per thread (no spills) ============
// block: 256 thr = 4 waves; tile 8x8 px, 1 image, 128 ch (zh half)
// lane: pr = tid&7 (px row), chg = tid>>3 (0..31); ch_l = chg + 32*j (j 0..3)
// LDS: act rows stride 84 (conflict-free), weights stride 76 (conflict-free)
__global__ __launch_bounds__(256) void conv1_k(const uint32_t* __restrict__ p1,
    const uint32_t* __restrict__ pw1, const short* __restrict__ corrG,
    short* __restrict__ S1, unsigned long long* __restrict__ st1) {
  __shared__ uint32_t actS[840];    // 10 rows x (10 cols x 8q + 4 pad)
  __shared__ uint32_t wtS[9728];    // [ch_l 128] x stride 76 (72 used)
  __shared__ short    corrS[1024];  // [ch_l 128][8]
  const int tid = threadIdx.x;
  const int bx = blockIdx.x;            // 0..48 tile
  const int ty = bx / 7, tx = bx % 7;
  const int n = blockIdx.y;             // image
  const int zh = blockIdx.z;            // 0..1 ch half
  const int h0 = ty * 8 - 1, w0 = tx * 8 - 1;
  for (int i = tid; i < 800; i += 256) {
    int r = i / 80, cq = i % 80;
    int c = cq >> 3;
    int hh = h0 + r, ww = w0 + c;
    uint32_t v = 0;
    if ((unsigned)hh < 56u && (unsigned)ww < 56u)
      v = p1[(size_t)(cq & 7) * NPIX + (size_t)n * HW + hh * 56 + ww];
    actS[r * 84 + cq] = v;
  }
  const uint32_t* pwB = pw1 + (size_t)zh * 9216;
  for (int i = tid; i < 2304; i += 256) {
    int ch = i / 18, t4 = (i % 18) * 4;
    *(uint4*)&wtS[ch * 76 + t4] = *(const uint4*)(pwB + ch * 72 + t4);
  }
  if (tid < 128)
    ((uint4*)corrS)[tid] = ((const uint4*)(corrG + zh * 1024))[tid];
  __syncthreads();

  const int pr = tid & 7;
  const int chg = tid >> 3;
  const uint32_t* wp = wtS + chg * 76;

  int acc[4][8];
#pragma unroll
  for (int j = 0; j < 4; ++j)
#pragma unroll
    for (int k = 0; k < 8; ++k) acc[j][k] = 0;

#pragma unroll 1
  for (int dh = 0; dh < 3; ++dh) {
#pragma unroll 1
    for (int q4 = 0; q4 < 2; ++q4) {
      uint4 a10[10];
      const uint32_t* ar = actS + (pr + dh) * 84 + q4 * 4;
#pragma unroll
      for (int c2 = 0; c2 < 10; ++c2) a10[c2] = *(const uint4*)(ar + c2 * 8);
#pragma unroll
      for (int dw = 0; dw < 3; ++dw) {
#pragma unroll
        for (int j = 0; j < 4; ++j) {
          uint4 w = *(const uint4*)(wp + j * 2432 + (dh * 3 + dw) * 8 + q4 * 4);
#pragma unroll
          for (int k = 0; k < 8; ++k) {
            uint4 a = a10[k + dw];
            int t = acc[j][k];
            t += __builtin_popcount(a.x ^ w.x);
            t += __builtin_popcount(a.y ^ w.y);
            t += __builtin_popcount(a.z ^ w.z);
            t += __builtin_popcount(a.w ^ w.w);
            acc[j][k] = t;
          }
        }
      }
    }
  }

  const int h = ty * 8 + pr;
  const bool hT = (h == 0), hB = (h == 55);
  const int slot = (bx + n * 49) & 63;
#pragma unroll
  for (int j = 0; j < 4; ++j) {
    const int ch_l = chg + 32 * j;
    const short* cw = &corrS[ch_l * 8];
    int cH = hT ? (int)cw[0] : (hB ? (int)cw[1] : 0);
    int s[8];
#pragma unroll
    for (int k = 0; k < 8; ++k) s[k] = 2304 - 2 * acc[j][k] + cH;
    if (tx == 0) s[0] += (int)cw[2] - (hT ? (int)cw[4] : (hB ? (int)cw[6] : 0));
    if (tx == 6) s[7] += (int)cw[3] - (hT ? (int)cw[5] : (hB ? (int)cw[7] : 0));
    int sm = 0, sq = 0;
#pragma unroll
    for (int k = 0; k < 8; ++k) { sm += s[k]; sq += s[k] * s[k]; }
    uint4 val;
    val.x = (uint32_t)(uint16_t)s[0] | ((uint32_t)(uint16_t)s[1] << 16);
    val.y = (uint32_t)(uint16_t)s[2] | ((uint32_t)(uint16_t)s[3] << 16);
    val.z = (uint32_t)(uint16_t)s[4] | ((uint32_t)(uint16_t)s[5] << 16);
    val.w = (uint32_t)(uint16_t)s[6] | ((uint32_t)(uint16_t)s[7] << 16);
    *(uint4*)&S1[(((size_t)n * 49 + bx) * 256 + zh * 128 + ch_l) * 64 + pr * 8] = val;
#pragma unroll
    for (int m = 1; m < 8; m <<= 1) { sm += __shfl_xor(sm, m, 64); sq += __shfl_xor(sq, m, 64); }
    if (pr == 0) {
      unsigned long long* st = st1 + ((size_t)(zh * 128 + ch_l) * 64 + slot) * 2;
      atomicAdd(&st[0], (unsigned long long)(long long)sm);
      atomicAdd(&st[1], (unsigned long long)(long long)sq);
    }
  }
}

// ============ BN finalize (parallel): fold to y = A*S + B ============
__global__ void bnfin_k(const unsigned long long* __restrict__ st, const float* __restrict__ sc,
                        const float* __restrict__ g, const float* __restrict__ b,
                        float* __restrict__ A, float* __restrict__ B) {
  const int c = blockIdx.x, l = threadIdx.x;
  long long sm = (long long)st[((size_t)c * 64 + l) * 2 + 0];
  long long sq = (long long)st[((size_t)c * 64 + l) * 2 + 1];
  for (int m = 1; m < 64; m <<= 1) { sm += __shfl_xor(sm, m, 64); sq += __shfl_xor(sq, m, 64); }
  if (l == 0) {
    const double M = (double)NPIX;
    double mS = (double)sm / M;
    double vS = (double)sq / M - mS * mS;
    double scale = (double)sc[c];
    double mean = scale * mS;
    double var = scale * scale * vS;
    double rstd = 1.0 / sqrt(var + 1e-5);
    double gd = (double)g[c];
    A[c] = (float)(gd * scale * rstd);
    B[c] = (float)((double)b[c] - gd * mean * rstd);
  }
}

// ============ pack2: elementwise chain -> sign bits, float4-vectorized ============
__global__ __launch_bounds__(256) void pack2_k(const float* __restrict__ x,
    const short* __restrict__ S1,
    const float* __restrict__ A1, const float* __restrict__ B1,
    const float* __restrict__ b1_2, const float* __restrict__ a1,
    const float* __restrict__ b1_3, const float* __restrict__ b2_1,
    uint32_t* __restrict__ p2) {
  const int j = blockIdx.y;
  const int gpx = blockIdx.x * 256 + threadIdx.x;
  const int n = gpx / 784;
  const int p4 = (gpx - n * 784) * 4;
  const int h = p4 / 56, w = p4 - (p4 / 56) * 56;
  const int tile = (h >> 3) * 7 + (w >> 3);
  const int px = (h & 7) * 8 + (w & 7);
  const float* xb = x + ((size_t)n * 256 + j * 32) * HW + p4;
  const short* s1b = S1 + (((size_t)n * 49 + tile) * 256 + j * 32) * 64 + px;
  uint32_t w0 = 0, w1 = 0, w2 = 0, w3 = 0;
#pragma unroll
  for (int cc = 0; cc < 32; ++cc) {
    int c = j * 32 + cc;
    float4 xv = *(const float4*)(xb + (size_t)cc * HW);
    short4 s1 = *(const short4*)(s1b + cc * 64);
    float Ac = A1[c], Bc = B1[c], p12 = b1_2[c], al = a1[c], p13 = b1_3[c], p21 = b2_1[c];
    float u, v, t;
    u = xv.x + (Ac * (float)s1.x + Bc) + p12; v = u >= 0.f ? u : al * u; t = v + p13 + p21;
    w0 |= (t >= 0.f) ? (1u << cc) : 0u;
    u = xv.y + (Ac * (float)s1.y + Bc) + p12; v = u >= 0.f ? u : al * u; t = v + p13 + p21;
    w1 |= (t >= 0.f) ? (1u << cc) : 0u;
    u = xv.z + (Ac * (float)s1.z + Bc) + p12; v = u >= 0.f ? u : al * u; t = v + p13 + p21;
    w2 |= (t >= 0.f) ? (1u << cc) : 0u;
    u = xv.w + (Ac * (float)s1.w + Bc) + p12; v = u >= 0.f ? u : al * u; t = v + p13 + p21;
    w3 |= (t >= 0.f) ? (1u << cc) : 0u;
  }
  uint4 o = {w0, w1, w2, w3};
  *(uint4*)&p2[(size_t)j * NPIX + gpx * 4] = o;
}

// ============ conv2: 1x1 binarized, swizzled act, interleaved channels ============
__global__ __launch_bounds__(256) void conv2_k(const uint32_t* __restrict__ p2,
                                               const uint32_t* __restrict__ pw2,
                                               short* __restrict__ S2,
                                               unsigned long long* __restrict__ st2) {
  __shared__ uint32_t actS[512];   // 64 px x 8 q, XOR-swizzled 16B groups
  __shared__ uint32_t wtS[1024];   // [ch_l 128][q 8]
  const int tid = threadIdx.x;
  const int bx = blockIdx.x;       // 0..1567 pixel group
  const int zh = blockIdx.y;
  const int pg0 = bx * 64;
  for (int i = tid; i < 512; i += 256) {
    int gq = i >> 2, ws_ = i & 3;
    int pxl = gq >> 1, q4 = gq & 1;
    int q = q4 * 4 + ws_;
    actS[((gq ^ ((gq >> 3) & 15)) << 2) + ws_] = p2[q * NPIX + pg0 + pxl];
  }
  if (tid < 256)
    ((uint4*)wtS)[tid] = ((const uint4*)(pw2 + zh * 1024))[tid];
  __syncthreads();
  const int pxg = tid & 15, chg = tid >> 4;
  int acc[8][4];
#pragma unroll
  for (int j = 0; j < 8; ++j)
#pragma unroll
    for (int k = 0; k < 4; ++k) acc[j][k] = 0;
#pragma unroll
  for (int q4 = 0; q4 < 2; ++q4) {
    uint4 a[4];
#pragma unroll
    for (int k = 0; k < 4; ++k) {
      int gq = 8 * pxg + 2 * k + q4;
      a[k] = *(const uint4*)&actS[(gq ^ pxg) << 2];
    }
#pragma unroll
    for (int j = 0; j < 8; ++j) {
      uint4 w = *(const uint4*)&wtS[(chg + 16 * j) * 8 + q4 * 4];
#pragma unroll
      for (int k = 0; k < 4; ++k) {
        int t = acc[j][k];
        t += __builtin_popcount(a[k].x ^ w.x);
        t += __builtin_popcount(a[k].y ^ w.y);
        t += __builtin_popcount(a[k].z ^ w.z);
        t += __builtin_popcount(a[k].w ^ w.w);
        acc[j][k] = t;
      }
    }
  }
  const int slot = bx & 63;
#pragma unroll
  for (int j = 0; j < 8; ++j) {
    const int c_l = chg + 16 * j;
    int s[4], sm = 0, sq = 0;
#pragma unroll
    for (int k = 0; k < 4; ++k) {
      s[k] = 256 - 2 * acc[j][k];
      sm += s[k]; sq += s[k] * s[k];
    }
    short4 o4;
    o4.x = (short)s[0]; o4.y = (short)s[1]; o4.z = (short)s[2]; o4.w = (short)s[3];
    *(short4*)&S2[(((size_t)bx * 256) + zh * 128 + c_l) * 64 + pxg * 4] = o4;
#pragma unroll
    for (int m = 1; m < 16; m <<= 1) { sm += __shfl_xor(sm, m, 64); sq += __shfl_xor(sq, m, 64); }
    if (pxg == 0) {
      unsigned long long* st = st2 + ((size_t)(zh * 128 + c_l) * 64 + slot) * 2;
      atomicAdd(&st[0], (unsigned long long)(long long)sm);
      atomicAdd(&st[1], (unsigned long long)(long long)sq);
    }
  }
}

// ============ final: recompute t, BN2 + residual + PReLU chain ============
__global__ __launch_bounds__(256) void final_k(const float* __restrict__ x,
    const short* __restrict__ S1, const short* __restrict__ S2,
    const float* __restrict__ A1, const float* __restrict__ B1,
    const float* __restrict__ b1_2, const float* __restrict__ a1, const float* __restrict__ b1_3,
    const float* __restrict__ A2, const float* __restrict__ B2,
    const float* __restrict__ b2_2, const float* __restrict__ a2, const float* __restrict__ b2_3,
    float* __restrict__ out) {
  const int gi = blockIdx.x * 256 + threadIdx.x;
  const int i4 = gi * 4;
  const int nc = i4 / 3136;
  const int p = i4 - nc * 3136;
  const int n = nc >> 8, c = nc & 255;
  const int h = p / 56, w = p - (p / 56) * 56;
  const int tile = (h >> 3) * 7 + (w >> 3);
  const int px = (h & 7) * 8 + (w & 7);
  short4 s1 = *(const short4*)&S1[(((size_t)n * 49 + tile) * 256 + c) * 64 + px];
  const int pg = n * 3136 + p;
  short4 s2 = *(const short4*)&S2[((size_t)(pg >> 6) * 256 + c) * 64 + (pg & 63)];
  float4 xv = *(const float4*)&x[i4];
  const float A1c = A1[c], B1c = B1[c], P12 = b1_2[c], AL1 = a1[c], P13 = b1_3[c];
  const float A2c = A2[c], B2c = B2[c], P22 = b2_2[c], AL2 = a2[c], P23 = b2_3[c];
  float xs[4] = {xv.x, xv.y, xv.z, xv.w};
  float f1[4] = {(float)s1.x, (float)s1.y, (float)s1.z, (float)s1.w};
  float f2[4] = {(float)s2.x, (float)s2.y, (float)s2.z, (float)s2.w};
  float o[4];
#pragma unroll
  for (int e = 0; e < 4; ++e) {
    float u = xs[e] + (A1c * f1[e] + B1c);
    u = u + P12;
    float v = u >= 0.0f ? u : AL1 * u;
    float t = v + P13;
    float z = (A2c * f2[e] + B2c) + t;
    z = z + P22;
    float vv = z >= 0.0f ? z : AL2 * z;
    o[e] = vv + P23;
  }
  float4 ov = {o[0], o[1], o[2], o[3]};
  *(float4*)&out[i4] = ov;
}

extern "C" void kernel_launch(void* const* d_in, const int* in_sizes, int n_in,
                              void* d_out, int out_size, void* d_ws, size_t ws_size,
                              hipStream_t stream) {
  const float* x    = (const float*)d_in[0];
  const float* b1_1 = (const float*)d_in[1];
  const float* w3x3 = (const float*)d_in[2];
  const float* bn1g = (const float*)d_in[3];
  const float* bn1b = (const float*)d_in[4];
  const float* b1_2 = (const float*)d_in[5];
  const float* a1   = (const float*)d_in[6];
  const float* b1_3 = (const float*)d_in[7];
  const float* b2_1 = (const float*)d_in[8];
  const float* wres = (const float*)d_in[9];
  const float* bn2g = (const float*)d_in[10];
  const float* bn2b = (const float*)d_in[11];
  const float* b2_2 = (const float*)d_in[12];
  const float* a2   = (const float*)d_in[13];
  const float* b2_3 = (const float*)d_in[14];

  char* ws = (char*)d_ws;
  uint32_t* pw1 = (uint32_t*)(ws + OFF_PW1);
  uint32_t* pw2 = (uint32_t*)(ws + OFF_PW2);
  short* corrG = (short*)(ws + OFF_CORR);
  float* sc1 = (float*)(ws + OFF_SC1);
  float* sc2 = (float*)(ws + OFF_SC2);
  float* A1 = (float*)(ws + OFF_A1);
  float* B1 = (float*)(ws + OFF_B1);
  float* A2 = (float*)(ws + OFF_A2);
  float* B2 = (float*)(ws + OFF_B2);
  unsigned long long* st1 = (unsigned long long*)(ws + OFF_ST);
  unsigned long long* st2 = (unsigned long long*)(ws + OFF_ST + 262144u);
  uint32_t* p1 = (uint32_t*)(ws + OFF_P1);
  uint32_t* p2 = (uint32_t*)(ws + OFF_P2);
  short* S1 = (short*)(ws + OFF_S1);
  short* S2 = (short*)(ws + OFF_S2);

  hipMemsetAsync(ws + OFF_ST, 0, ST_BYTES, stream);
  prep_w_k<<<256, 64, 0, stream>>>(w3x3, wres, pw1, pw2, sc1, sc2, corrG);
  pack1_k<<<dim3(98, 8), 256, 0, stream>>>(x, b1_1, p1);
  conv1_k<<<dim3(49, 32, 2), 256, 0, stream>>>(p1, pw1, corrG, S1, st1);
  bnfin_k<<<256, 64, 0, stream>>>(st1, sc1, bn1g, bn1b, A1, B1);
  pack2_k<<<dim3(98, 8), 256, 0, stream>>>(x, S1, A1, B1, b1_2, a1, b1_3, b2_1, p2);
  conv2_k<<<dim3(1568, 2), 256, 0, stream>>>(p2, pw2, S2, st2);
  bnfin_k<<<256, 64, 0, stream>>>(st2, sc2, bn2g, bn2b, A2, B2);
  final_k<<<25088, 256, 0, stream>>>(x, S1, S2, A1, B1, b1_2, a1, b1_3,
                                     A2, B2, b2_2, a2, b2_3, (float*)d_out);
}